// Round 7
// baseline (11136.242 us; speedup 1.0000x reference)
//
#include <hip/hip_runtime.h>
#include <math.h>

#define TT 512
#define BB 64
#define FF 256
#define HH 1024
#define NBLK 256
#define NCHE 5   // encoder K-chunks: 256 (x) + 4*256 (h)
#define NCHD 8   // decoder K-chunks: 4*256 (enc h) + 4*256 (dec h)
#define NMIR 8   // flag mirror pages (spread poll traffic)

typedef __attribute__((ext_vector_type(8))) short short8;
typedef __attribute__((ext_vector_type(4))) float f32x4;

__device__ __forceinline__ unsigned short f2bf(float f) {
    unsigned u = __float_as_uint(f);
    u += 0x7FFFu + ((u >> 16) & 1u);   // RNE (finite inputs only)
    return (unsigned short)(u >> 16);
}
__device__ __forceinline__ float bf2f(unsigned short u) {
    return __uint_as_float((unsigned)u << 16);
}

// ---------------------------------------------------------------------------
// x[b][t][f] fp32 -> xB[t][b][f] bf16 (batch-major per step). xB lives in
// d_out (dead until out_proj overwrites it).
// ---------------------------------------------------------------------------
__global__ __launch_bounds__(256) void k_cast_x(const float* __restrict__ x,
                                                unsigned short* __restrict__ xB) {
    int t = blockIdx.x;
    #pragma unroll
    for (int i = 0; i < 16; ++i) {
        int id = threadIdx.x + i * 256;
        int b  = id >> 6;
        int f4 = (id & 63) << 2;
        float4 v = *(const float4*)(x + ((size_t)b * TT + t) * FF + f4);
        ushort4 o;
        o.x = f2bf(v.x); o.y = f2bf(v.y); o.z = f2bf(v.z); o.w = f2bf(v.w);
        *(ushort4*)(xB + ((size_t)t * BB + b) * FF + f4) = o;
    }
}

__global__ __launch_bounds__(256) void k_wcast(const float* __restrict__ in,
                                               unsigned short* __restrict__ out,
                                               int n4) {
    int stride = gridDim.x * 256;
    for (int i = blockIdx.x * 256 + threadIdx.x; i < n4; i += stride) {
        float4 v = ((const float4*)in)[i];
        ushort4 o;
        o.x = f2bf(v.x); o.y = f2bf(v.y); o.z = f2bf(v.z); o.w = f2bf(v.w);
        ((ushort4*)out)[i] = o;
    }
}

// ---------------------------------------------------------------------------
// Per-PLANE per-wave flags, 2-hop chain.
// Key fact: wave w of block j produces h[rows 16w..16w+15][units 4j..4j+3];
// consumer wave w' reads only rows 16w'..+15 -> depends ONLY on same-w waves
// of all 256 blocks. Four independent 256-flag barriers (planes), no
// __syncthreads, no aggregator, no mirror hop in the chain.
//   producer : (h sc1 stores from prev step drain under A1 phase) ->
//              vmcnt(0) -> lanes 0..7 store flag to 8 mirror pages.
//   consumer : polls 4 flags/lane (blocks lane,lane+64,+128,+192) of its
//              plane on mirror page (blockIdx&7). 1KB footprint/wave/round
//              spread across pages -> no poll storm (round-4 fix).
// Ordering: h(sc1, coherence point) -> vmcnt0 -> flag store; consumer
// atomic-load sees flag -> compiler barrier -> normal loads of fresh ring
// addresses (no-invalidate scheme proven by rounds 2/4/5 passing).
// Liveness: monotone single-writer flags; wave publishes s before waiting
// on s; planes independent. Deadlock-free by induction.
// ---------------------------------------------------------------------------
__device__ __forceinline__ void pubwave(unsigned* __restrict__ flags,
                                        int w, int blk, unsigned val, int lane) {
    asm volatile("s_waitcnt vmcnt(0)" ::: "memory");   // drain prev h stores
    if (lane < NMIR)
        __hip_atomic_store(flags + lane * 1024 + w * 256 + blk, val,
                           __ATOMIC_RELAXED, __HIP_MEMORY_SCOPE_AGENT);
}

__device__ __forceinline__ void waitplane(const unsigned* __restrict__ flags,
                                          int mpage, int w, int lane,
                                          unsigned tgt) {
    const unsigned* fp = flags + mpage * 1024 + w * 256;
    for (;;) {
        bool ok = true;
        #pragma unroll
        for (int k = 0; k < 4; ++k) {
            unsigned v = __hip_atomic_load(fp + k * 64 + lane,
                                           __ATOMIC_RELAXED,
                                           __HIP_MEMORY_SCOPE_AGENT);
            ok &= (v >= tgt);
        }
        if (__all(ok)) break;
        __builtin_amdgcn_s_sleep(1);
    }
    asm volatile("" ::: "memory");   // keep A2 loads below the wait
}

// ---------------------------------------------------------------------------
// One LSTM step. Order: A1 loads+MFMA (hides prev h-store ack) -> publish
// prev-step flag -> wait plane -> A2 loads+MFMA -> epilogue + sc1 h-store
// (ack deferred to next step's publish). Accumulation order identical to
// the verified kernel (c ascending, accA/accB by f parity).
// ---------------------------------------------------------------------------
template <int NCH, int C1>
__device__ __forceinline__ void lstm_step(
    const short8* __restrict__ sW,
    const unsigned short* __restrict__ A1, int K1,
    const unsigned short* __restrict__ A2, int K2,
    const f32x4 bias, float& creg,
    unsigned short* __restrict__ hOut,        // [BB][HH] bf16 (fresh ring slot)
    unsigned* __restrict__ flags, unsigned sv,  // step value; 0 = no pub/wait
    int mpage, int blk, int w,
    int lane, int q, int n, int j0, int u, int b)
{
    short8 av[3][8];
    auto aload = [&](short8* dst, int c) {
        const unsigned short* ap = (c < C1)
            ? A1 + (size_t)b * K1 + (size_t)c * 256
            : A2 + (size_t)b * K2 + (size_t)(c - C1) * 256;
        ap += q * 8;
        #pragma unroll
        for (int f = 0; f < 8; ++f) dst[f] = *(const short8*)(ap + f * 32);
    };

    f32x4 accA = {0.f, 0.f, 0.f, 0.f};
    f32x4 accB = {0.f, 0.f, 0.f, 0.f};

    // ---- phase 1: A1 chunks (no h_{t-1} dependency) ----
    aload(av[0], 0);
    if (C1 > 1) aload(av[1], 1);
    #pragma unroll
    for (int c = 0; c < C1; ++c) {
        if (c + 2 < C1) aload(av[(c + 2) % 3], c + 2);
        const short8* cur = av[c % 3];
        #pragma unroll
        for (int f = 0; f < 8; ++f) {
            short8 wv = sW[(c * 8 + f) * 64 + lane];
            if (f & 1) accB = __builtin_amdgcn_mfma_f32_16x16x32_bf16(wv, cur[f], accB, 0, 0, 0);
            else       accA = __builtin_amdgcn_mfma_f32_16x16x32_bf16(wv, cur[f], accA, 0, 0, 0);
        }
    }

    // ---- publish previous step's h, then wait for peers ----
    if (sv) {
        pubwave(flags, w, blk, sv, lane);
        waitplane(flags, mpage, w, lane, sv);
    }

    // ---- phase 2: A2 chunks (h_{t-1}) ----
    if (NCH > C1) {
        aload(av[C1 % 3], C1);
        if (NCH > C1 + 1) aload(av[(C1 + 1) % 3], C1 + 1);
        #pragma unroll
        for (int c = C1; c < NCH; ++c) {
            if (c + 2 < NCH) aload(av[(c + 2) % 3], c + 2);
            const short8* cur = av[c % 3];
            #pragma unroll
            for (int f = 0; f < 8; ++f) {
                short8 wv = sW[(c * 8 + f) * 64 + lane];
                if (f & 1) accB = __builtin_amdgcn_mfma_f32_16x16x32_bf16(wv, cur[f], accB, 0, 0, 0);
                else       accA = __builtin_amdgcn_mfma_f32_16x16x32_bf16(wv, cur[f], accA, 0, 0, 0);
            }
        }
    }
    f32x4 acc = accA + accB;

    float pi = acc[0] + bias[0];
    float pf = acc[1] + bias[1];
    float pg = acc[2] + bias[2];
    float po = acc[3] + bias[3];
    float iv = 1.f / (1.f + __expf(-pi));
    float fv = 1.f / (1.f + __expf(-pf));
    float gv = tanhf(pg);
    float ov = 1.f / (1.f + __expf(-po));
    float cn = fv * creg + iv * gv;
    creg = cn;
    float hn = ov * tanhf(cn);

    // pack 4 gate-units (q=0..3) for batch row b into one u64, write-through
    unsigned hv = (unsigned)f2bf(hn);
    unsigned v0 = (unsigned)__shfl((int)hv, n);
    unsigned v1 = (unsigned)__shfl((int)hv, n + 16);
    unsigned v2 = (unsigned)__shfl((int)hv, n + 32);
    unsigned v3 = (unsigned)__shfl((int)hv, n + 48);
    if (q == 0) {
        unsigned long long pk = (unsigned long long)(v0 | (v1 << 16)) |
                                ((unsigned long long)(v2 | (v3 << 16)) << 32);
        __hip_atomic_store((unsigned long long*)(hOut + (size_t)b * HH + j0), pk,
                           __ATOMIC_RELAXED, __HIP_MEMORY_SCOPE_AGENT);
    }
    // no ack here: drains under next step's A1 phase, acked at pubwave
}

// ---------------------------------------------------------------------------
// Persistent kernel: 512 enc + 512 dec steps. 256 blocks x 4 waves (4 hidden
// units x 16-batch-row planes). Weights staged to LDS once (104KB). Cell
// state c lives in a register the whole time. No __syncthreads in the loop.
// ---------------------------------------------------------------------------
__global__ __launch_bounds__(256, 1) void k_lstm_persist(
    const unsigned short* __restrict__ xB,     // [TT][BB][FF]
    const unsigned short* __restrict__ WihE,   // [4H][FF] bf16
    const unsigned short* __restrict__ WhhE,   // [4H][HH] bf16
    const float* __restrict__ bE,
    const unsigned short* __restrict__ WihD,   // [4H][HH] bf16
    const unsigned short* __restrict__ WhhD,   // [4H][HH] bf16
    const float* __restrict__ bD,
    unsigned short* __restrict__ encB,         // [TT][BB][HH] bf16 ring
    unsigned short* __restrict__ decR,         // [TT][BB][HH] bf16 ring
    unsigned* __restrict__ flags)              // u32[NMIR][4][256]
{
    __shared__ short8 sWe[NCHE * 8 * 64];      // 40KB
    __shared__ short8 sWd[NCHD * 8 * 64];      // 64KB

    const int tid  = threadIdx.x;
    const int lane = tid & 63;
    const int w    = tid >> 6;
    const int q    = lane >> 4;
    const int n    = lane & 15;
    const int j0   = blockIdx.x * 4;
    const int rrow = (n & 3) * HH + j0 + (n >> 2);
    const size_t SB = (size_t)BB * HH;
    const int blk   = blockIdx.x;
    const int mpage = blockIdx.x & (NMIR - 1);

    // ---- stage BOTH weight sets into LDS, fragment order (once) ----
    #pragma unroll
    for (int i = 0; i < 2 * NCHE; ++i) {
        int g = i * 4 + w;                     // frag id 0..NCHE*8-1
        int c = g >> 3, f = g & 7;
        const unsigned short* Wp; int Ks; int cl;
        if (c < 1) { Wp = WihE; Ks = FF; cl = c; }
        else       { Wp = WhhE; Ks = HH; cl = c - 1; }
        sWe[g * 64 + lane] =
            *(const short8*)(Wp + (size_t)rrow * Ks + (size_t)cl * 256 + f * 32 + q * 8);
    }
    #pragma unroll
    for (int i = 0; i < 2 * NCHD; ++i) {
        int g = i * 4 + w;
        int c = g >> 3, f = g & 7;
        const unsigned short* Wp; int cl;
        if (c < 4) { Wp = WihD; cl = c; }
        else       { Wp = WhhD; cl = c - 4; }
        sWd[g * 64 + lane] =
            *(const short8*)(Wp + (size_t)rrow * HH + (size_t)cl * 256 + f * 32 + q * 8);
    }
    __syncthreads();

    const int u = j0 + q;
    const int b = w * 16 + n;
    const f32x4 biasE = {bE[u], bE[HH + u], bE[2 * HH + u], bE[3 * HH + u]};
    const f32x4 biasD = {bD[u], bD[HH + u], bD[2 * HH + u], bD[3 * HH + u]};

    float creg = 0.f;

    // ---- encoder: global step s publishes h of s-1 with value s, waits s ----
    lstm_step<1, 1>(sWe, xB, FF, xB, FF, biasE, creg,
                    encB, flags, 0u, mpage, blk, w, lane, q, n, j0, u, b);
    for (int t = 1; t < TT; ++t) {
        lstm_step<NCHE, 1>(sWe, xB + (size_t)t * BB * FF, FF,
                           encB + (size_t)(t - 1) * SB, HH,
                           biasE, creg, encB + (size_t)t * SB,
                           flags, (unsigned)t, mpage, blk, w,
                           lane, q, n, j0, u, b);
    }

    // ---- decoder: h0 = enc h_T (encB[TT-1]), c continues in creg ----
    for (int t = 0; t < TT; ++t) {
        const unsigned short* A2 = (t == 0) ? encB + (size_t)(TT - 1) * SB
                                            : decR + (size_t)(t - 1) * SB;
        lstm_step<NCHD, 4>(sWd, encB + (size_t)t * SB, HH, A2, HH,
                           biasD, creg, decR + (size_t)t * SB,
                           flags, (unsigned)(TT + t), mpage, blk, w,
                           lane, q, n, j0, u, b);
    }
    // decR stores reach the coherence point (sc1); dispatch boundary
    // handles visibility for out_proj.
}

// ---------------------------------------------------------------------------
// Output projection from the bf16 decoder ring decR [TT][BB][HH].
// ---------------------------------------------------------------------------
__global__ __launch_bounds__(256) void k_out_proj_r(
    const unsigned short* __restrict__ decR,  // [TT][BB][HH]
    const float* __restrict__ Wout,           // [FF][HH]
    const float* __restrict__ bout,           // [FF]
    float* __restrict__ out)                  // [BB][TT][FF]
{
    int t  = blockIdx.x;
    int fg = blockIdx.y;
    const int lane = threadIdx.x & 63;
    const int wv   = __builtin_amdgcn_readfirstlane(threadIdx.x >> 6);
    const int f0   = fg * 64 + wv * 16;
    const unsigned short* a = decR + ((size_t)t * BB + lane) * HH;

    float acc[16];
    #pragma unroll
    for (int i = 0; i < 16; ++i) acc[i] = bout[f0 + i];

    for (int k8 = 0; k8 < HH / 8; ++k8) {
        short8 hv8 = *(const short8*)(a + k8 * 8);
        #pragma unroll
        for (int uu = 0; uu < 8; ++uu) {
            float hv = bf2f((unsigned short)hv8[uu]);
            #pragma unroll
            for (int i = 0; i < 16; ++i)
                acc[i] = fmaf(Wout[(size_t)(f0 + i) * HH + k8 * 8 + uu], hv, acc[i]);
        }
    }

    float* op = out + ((size_t)lane * TT + t) * FF + f0;
    #pragma unroll
    for (int i = 0; i < 16; i += 4) {
        float4 v = make_float4(acc[i], acc[i + 1], acc[i + 2], acc[i + 3]);
        *(float4*)(op + i) = v;
    }
}

// ---------------------------------------------------------------------------
// FALLBACK path (small workspace): round-4 verified per-step kernels.
// ---------------------------------------------------------------------------
template <int NCH>
__global__ __launch_bounds__(256) void k_step_lds(
    const unsigned short* __restrict__ A1, const unsigned short* __restrict__ W1, int K1,
    const unsigned short* __restrict__ A2, const unsigned short* __restrict__ W2, int K2,
    int C1,
    const float* __restrict__ bias,
    float* __restrict__ Cbuf,
    unsigned short* __restrict__ hOut,
    float* __restrict__ chunkOut)
{
    __shared__ short8 sW[NCH * 8 * 64];

    const int tid  = threadIdx.x;
    const int lane = tid & 63;
    const int w    = tid >> 6;
    const int q    = lane >> 4;
    const int n    = lane & 15;
    const int j0   = blockIdx.x * 4;
    const int rrow = (n & 3) * HH + j0 + (n >> 2);

    short8 av[3][8];

    auto aload = [&](short8* dst, int c) {
        const unsigned short* ap = (c < C1)
            ? A1 + (size_t)(w * 16 + n) * K1 + (size_t)c * 256
            : A2 + (size_t)(w * 16 + n) * K2 + (size_t)(c - C1) * 256;
        ap += q * 8;
        #pragma unroll
        for (int f = 0; f < 8; ++f) dst[f] = *(const short8*)(ap + f * 32);
    };

    aload(av[0], 0);
    if (NCH > 1) aload(av[1], 1);

    #pragma unroll
    for (int i = 0; i < 2 * NCH; ++i) {
        int g = i * 4 + w;
        int c = g >> 3, f = g & 7;
        const unsigned short* Wp; int Ks; int cl;
        if (c < C1) { Wp = W1; Ks = K1; cl = c; }
        else        { Wp = W2; Ks = K2; cl = c - C1; }
        sW[g * 64 + lane] =
            *(const short8*)(Wp + (size_t)rrow * Ks + (size_t)cl * 256 + f * 32 + q * 8);
    }
    __syncthreads();

    f32x4 accA = {0.f, 0.f, 0.f, 0.f};
    f32x4 accB = {0.f, 0.f, 0.f, 0.f};
    #pragma unroll
    for (int c = 0; c < NCH; ++c) {
        if (c + 2 < NCH) aload(av[(c + 2) % 3], c + 2);
        const short8* cur = av[c % 3];
        #pragma unroll
        for (int f = 0; f < 8; ++f) {
            short8 wv = sW[(c * 8 + f) * 64 + lane];
            if (f & 1) accB = __builtin_amdgcn_mfma_f32_16x16x32_bf16(wv, cur[f], accB, 0, 0, 0);
            else       accA = __builtin_amdgcn_mfma_f32_16x16x32_bf16(wv, cur[f], accA, 0, 0, 0);
        }
    }
    f32x4 acc = accA + accB;

    const int u = j0 + q;
    const int b = w * 16 + n;
    float pi = acc[0] + bias[u];
    float pf = acc[1] + bias[HH + u];
    float pg = acc[2] + bias[2 * HH + u];
    float po = acc[3] + bias[3 * HH + u];
    float iv = 1.f / (1.f + __expf(-pi));
    float fv = 1.f / (1.f + __expf(-pf));
    float gv = tanhf(pg);
    float ov = 1.f / (1.f + __expf(-po));
    size_t cix = (size_t)u * BB + b;
    float c  = Cbuf[cix];
    float cn = fv * c + iv * gv;
    Cbuf[cix] = cn;
    float hn = ov * tanhf(cn);
    hOut[(size_t)b * HH + u] = f2bf(hn);
    if (chunkOut) chunkOut[cix] = hn;
}

__device__ __forceinline__ void seg_f32(const unsigned short* __restrict__ ap0,
                                        const float* __restrict__ wp0,
                                        int nch, f32x4& acc) {
    const unsigned short* ap = ap0;
    const float* wp = wp0;
    #pragma unroll 2
    for (int c = 0; c < nch; ++c) {
        float4 wa = *(const float4*)wp;
        float4 wb = *(const float4*)(wp + 4);
        short8 av = *(const short8*)ap;
        short8 wv;
        wv[0] = (short)f2bf(wa.x); wv[1] = (short)f2bf(wa.y);
        wv[2] = (short)f2bf(wa.z); wv[3] = (short)f2bf(wa.w);
        wv[4] = (short)f2bf(wb.x); wv[5] = (short)f2bf(wb.y);
        wv[6] = (short)f2bf(wb.z); wv[7] = (short)f2bf(wb.w);
        acc = __builtin_amdgcn_mfma_f32_16x16x32_bf16(wv, av, acc, 0, 0, 0);
        ap += 32; wp += 32;
    }
}

__global__ __launch_bounds__(256) void k_step_f32w(
    const unsigned short* __restrict__ A1, const float* __restrict__ W1, int K1,
    const unsigned short* __restrict__ A2, const float* __restrict__ W2, int K2,
    const float* __restrict__ bias,
    float* __restrict__ Cbuf, unsigned short* __restrict__ hOut,
    float* __restrict__ chunkOut)
{
    const int tid  = threadIdx.x;
    const int lane = tid & 63;
    const int w    = tid >> 6;
    const int q    = lane >> 4;
    const int n    = lane & 15;
    const int j0   = blockIdx.x * 4;
    const int rrow = (n & 3) * HH + j0 + (n >> 2);

    f32x4 acc = {0.f, 0.f, 0.f, 0.f};
    seg_f32(A1 + (size_t)(w * 16 + n) * K1 + q * 8,
            W1 + (size_t)rrow * K1 + q * 8, K1 >> 5, acc);
    if (K2)
        seg_f32(A2 + (size_t)(w * 16 + n) * HH + q * 8,
                W2 + (size_t)rrow * HH + q * 8, HH >> 5, acc);

    const int u = j0 + q;
    const int b = w * 16 + n;
    float pi = acc[0] + bias[u];
    float pf = acc[1] + bias[HH + u];
    float pg = acc[2] + bias[2 * HH + u];
    float po = acc[3] + bias[3 * HH + u];
    float iv = 1.f / (1.f + __expf(-pi));
    float fv = 1.f / (1.f + __expf(-pf));
    float gv = tanhf(pg);
    float ov = 1.f / (1.f + __expf(-po));
    size_t cix = (size_t)u * BB + b;
    float c  = Cbuf[cix];
    float cn = fv * c + iv * gv;
    Cbuf[cix] = cn;
    float hn = ov * tanhf(cn);
    hOut[(size_t)b * HH + u] = f2bf(hn);
    if (chunkOut) chunkOut[cix] = hn;
}

__global__ __launch_bounds__(256) void k_out_proj(
    const float* __restrict__ chunk,  // [C][HH][BB]
    const float* __restrict__ Wout,
    const float* __restrict__ bout,
    float* __restrict__ out,
    int t0)
{
    int tl = blockIdx.x;
    int t  = t0 + tl;
    int fg = blockIdx.y;
    const int lane = threadIdx.x & 63;
    const int wv   = __builtin_amdgcn_readfirstlane(threadIdx.x >> 6);
    const int f0   = fg * 64 + wv * 16;
    const float* a = chunk + (size_t)tl * HH * BB;

    float acc[16];
    #pragma unroll
    for (int i = 0; i < 16; ++i) acc[i] = bout[f0 + i];

    for (int k = 0; k < HH; k += 4) {
        #pragma unroll
        for (int u = 0; u < 4; ++u) {
            float hv = a[(size_t)(k + u) * BB + lane];
            #pragma unroll
            for (int i = 0; i < 16; ++i)
                acc[i] = fmaf(Wout[(size_t)(f0 + i) * HH + k + u], hv, acc[i]);
        }
    }

    float* op = out + ((size_t)lane * TT + t) * FF + f0;
    #pragma unroll
    for (int i = 0; i < 16; i += 4) {
        float4 v = make_float4(acc[i], acc[i + 1], acc[i + 2], acc[i + 3]);
        *(float4*)(op + i) = v;
    }
}

// ---------------------------------------------------------------------------
extern "C" void kernel_launch(void* const* d_in, const int* in_sizes, int n_in,
                              void* d_out, int out_size, void* d_ws, size_t ws_size,
                              hipStream_t stream) {
    const float* x     = (const float*)d_in[0];
    const float* Wih_e = (const float*)d_in[1];
    const float* Whh_e = (const float*)d_in[2];
    const float* b_e   = (const float*)d_in[3];
    const float* Wih_d = (const float*)d_in[4];
    const float* Whh_d = (const float*)d_in[5];
    const float* b_d   = (const float*)d_in[6];
    const float* Wout  = (const float*)d_in[7];
    const float* bout  = (const float*)d_in[8];
    float* out = (float*)d_out;

    const size_t SB = (size_t)BB * HH;            // 65536 elems per state

    unsigned short* xB = (unsigned short*)d_out;  // [TT][BB][FF] bf16

    // ================= persistent-kernel tier (~154MB ws) =================
    {
        char* p = (char*)d_ws;
        unsigned* flags = (unsigned*)p; p += 32768; // u32[8][4][256] mirrors
        unsigned short* encB  = (unsigned short*)p; p += (size_t)TT * SB * 2;   // 64MB
        unsigned short* decR  = (unsigned short*)p; p += (size_t)TT * SB * 2;   // 64MB
        unsigned short* WihEb = (unsigned short*)p; p += (size_t)4 * HH * FF * 2;
        unsigned short* WhhEb = (unsigned short*)p; p += (size_t)4 * HH * HH * 2;
        unsigned short* WihDb = (unsigned short*)p; p += (size_t)4 * HH * HH * 2;
        unsigned short* WhhDb = (unsigned short*)p; p += (size_t)4 * HH * HH * 2;
        size_t need = (size_t)(p - (char*)d_ws);

        if (ws_size >= need) {
            hipMemsetAsync(flags, 0, 32768, stream);
            k_cast_x<<<TT, 256, 0, stream>>>(x, xB);
            k_wcast<<<1024, 256, 0, stream>>>(Wih_e, WihEb, 4 * HH * FF / 4);
            k_wcast<<<1024, 256, 0, stream>>>(Whh_e, WhhEb, 4 * HH * HH / 4);
            k_wcast<<<1024, 256, 0, stream>>>(Wih_d, WihDb, 4 * HH * HH / 4);
            k_wcast<<<1024, 256, 0, stream>>>(Whh_d, WhhDb, 4 * HH * HH / 4);

            void* args[] = {
                (void*)&xB, (void*)&WihEb, (void*)&WhhEb, (void*)&b_e,
                (void*)&WihDb, (void*)&WhhDb, (void*)&b_d,
                (void*)&encB, (void*)&decR, (void*)&flags};
            hipLaunchCooperativeKernel((const void*)k_lstm_persist,
                                       dim3(NBLK), dim3(256), args, 0, stream);

            k_out_proj_r<<<dim3(TT, 4), 256, 0, stream>>>(decR, Wout, bout, out);
            return;
        }
    }

    // ================= fallback: round-4 verified path =================
    char* p = (char*)d_ws;
    unsigned short* encB  = (unsigned short*)p; p += (size_t)TT * SB * 2;
    unsigned short* dech0 = (unsigned short*)p; p += SB * 2;
    unsigned short* dech1 = (unsigned short*)p; p += SB * 2;
    float* cbuf = (float*)p; p += SB * 4;
    size_t used  = (size_t)(p - (char*)d_ws);
    size_t avail = ws_size > used ? ws_size - used : 0;

    const size_t WE_B = ((size_t)4 * HH * FF + (size_t)4 * HH * HH) * 2;
    const size_t WD_B = ((size_t)4 * HH * HH) * 2 * 2;
    const size_t CH8  = (size_t)8 * SB * 4;

    bool wbAll = (avail >= WE_B + WD_B + CH8);
    bool wbEnc = wbAll || (avail >= WE_B + CH8);

    unsigned short *WihEb = 0, *WhhEb = 0, *WihDb = 0, *WhhDb = 0;
    if (wbEnc) {
        WihEb = (unsigned short*)p; p += (size_t)4 * HH * FF * 2;
        WhhEb = (unsigned short*)p; p += (size_t)4 * HH * HH * 2;
        avail -= WE_B;
    }
    if (wbAll) {
        WihDb = (unsigned short*)p; p += (size_t)4 * HH * HH * 2;
        WhhDb = (unsigned short*)p; p += (size_t)4 * HH * HH * 2;
        avail -= WD_B;
    }
    int C = 8;
    if      (avail >= (size_t)64 * SB * 4) C = 64;
    else if (avail >= (size_t)32 * SB * 4) C = 32;
    else if (avail >= (size_t)16 * SB * 4) C = 16;
    float* chunk = (float*)p;

    hipMemsetAsync(cbuf, 0, SB * 4, stream);
    k_cast_x<<<TT, 256, 0, stream>>>(x, xB);
    if (wbEnc) {
        k_wcast<<<1024, 256, 0, stream>>>(Wih_e, WihEb, 4 * HH * FF / 4);
        k_wcast<<<1024, 256, 0, stream>>>(Whh_e, WhhEb, 4 * HH * HH / 4);
    }
    if (wbAll) {
        k_wcast<<<1024, 256, 0, stream>>>(Wih_d, WihDb, 4 * HH * HH / 4);
        k_wcast<<<1024, 256, 0, stream>>>(Whh_d, WhhDb, 4 * HH * HH / 4);
    }

    for (int t = 0; t < TT; ++t) {
        const unsigned short* A1 = xB + (size_t)t * BB * FF;
        const unsigned short* A2 = t ? encB + (size_t)(t - 1) * SB : (unsigned short*)0;
        unsigned short* hOut = encB + (size_t)t * SB;
        if (wbEnc) {
            if (t == 0)
                k_step_lds<1><<<256, 256, 0, stream>>>(A1, WihEb, FF, A2, WhhEb, HH,
                                                       1, b_e, cbuf, hOut, (float*)0);
            else
                k_step_lds<5><<<256, 256, 0, stream>>>(A1, WihEb, FF, A2, WhhEb, HH,
                                                       1, b_e, cbuf, hOut, (float*)0);
        } else {
            k_step_f32w<<<256, 256, 0, stream>>>(A1, Wih_e, FF, A2, Whh_e,
                                                 t ? HH : 0, b_e, cbuf, hOut, (float*)0);
        }
    }

    for (int t = 0; t < TT; ++t) {
        const unsigned short* A1 = encB + (size_t)t * SB;
        const unsigned short* A2 = (t == 0) ? encB + (size_t)(TT - 1) * SB
                                            : ((t & 1) ? dech1 : dech0);
        unsigned short* hOut = ((t + 1) & 1) ? dech1 : dech0;
        int l = t & (C - 1);
        float* ch = chunk + (size_t)l * SB;
        if (wbAll)
            k_step_lds<8><<<256, 256, 0, stream>>>(A1, WihDb, HH, A2, WhhDb, HH,
                                                   4, b_d, cbuf, hOut, ch);
        else
            k_step_f32w<<<256, 256, 0, stream>>>(A1, Wih_d, FF, A2, Whh_d, HH,
                                                 b_d, cbuf, hOut, ch);
        if (l == C - 1)
            k_out_proj<<<dim3(C, 4), 256, 0, stream>>>(chunk, Wout, bout, out,
                                                       t - (C - 1));
    }
}

// Round 10
// 9657.543 us; speedup vs baseline: 1.1531x; 1.1531x over previous
//
#include <hip/hip_runtime.h>
#include <math.h>

#define TT 512
#define BB 64
#define FF 256
#define HH 1024
#define NBLK 256
#define NCHE 5   // encoder K-chunks: 256 (x) + 4*256 (h)
#define NCHD 8   // decoder K-chunks: 4*256 (enc h) + 4*256 (dec h)

typedef __attribute__((ext_vector_type(8))) short short8;
typedef __attribute__((ext_vector_type(4))) float f32x4;

__device__ __forceinline__ unsigned short f2bf(float f) {
    unsigned u = __float_as_uint(f);
    u += 0x7FFFu + ((u >> 16) & 1u);   // RNE (finite inputs only)
    return (unsigned short)(u >> 16);
}
__device__ __forceinline__ float bf2f(unsigned short u) {
    return __uint_as_float((unsigned)u << 16);
}

// ---------------------------------------------------------------------------
// x[b][t][f] fp32 -> xB[t][b][f] bf16. xB lives in d_out (dead until
// out_proj overwrites it).
// ---------------------------------------------------------------------------
__global__ __launch_bounds__(256) void k_cast_x(const float* __restrict__ x,
                                                unsigned short* __restrict__ xB) {
    int t = blockIdx.x;
    #pragma unroll
    for (int i = 0; i < 16; ++i) {
        int id = threadIdx.x + i * 256;
        int b  = id >> 6;
        int f4 = (id & 63) << 2;
        float4 v = *(const float4*)(x + ((size_t)b * TT + t) * FF + f4);
        ushort4 o;
        o.x = f2bf(v.x); o.y = f2bf(v.y); o.z = f2bf(v.z); o.w = f2bf(v.w);
        *(ushort4*)(xB + ((size_t)t * BB + b) * FF + f4) = o;
    }
}

__global__ __launch_bounds__(256) void k_wcast(const float* __restrict__ in,
                                               unsigned short* __restrict__ out,
                                               int n4) {
    int stride = gridDim.x * 256;
    for (int i = blockIdx.x * 256 + threadIdx.x; i < n4; i += stride) {
        float4 v = ((const float4*)in)[i];
        ushort4 o;
        o.x = f2bf(v.x); o.y = f2bf(v.y); o.z = f2bf(v.z); o.w = f2bf(v.w);
        ((ushort4*)out)[i] = o;
    }
}

// ---------------------------------------------------------------------------
// Sync = round-5 VERIFIED structure (single-writer flags + 16 group
// aggregators + 8 mirror pages), with ONE change: consumers wait PER CHUNK
// GROUP instead of on the full barrier.
//   producers : sc1 h-store -> (phase-1 overlap) -> vmcnt(0) -> lane-0 flag.
//   16 aggs   : wave 4 of every 16th block; agg g polls its 64 group flags,
//               then stores epoch e to mir[p*64+g] for all 8 pages.
//   consumers : A2 chunk c' needs units 256c'.. produced by blocks
//               64c'..64c'+63 = groups 4c'..4c'+3. waitgrp polls exactly
//               those 4 group epochs on mirror page (blockIdx&7), so MFMA on
//               early chunks absorbs stragglers in later groups.
// Certification is unchanged vs R5 (group epoch >= tgt before the chunk is
// loaded); only the wait granularity is finer. No-invalidate fresh-ring
// scheme proven by R2/R4/R5/R7 passing.
// ---------------------------------------------------------------------------
__device__ __forceinline__ void publish(unsigned* __restrict__ flags,
                                        int widx, unsigned val) {
    asm volatile("s_waitcnt vmcnt(0)" ::: "memory");
    if ((threadIdx.x & 63) == 0)
        __hip_atomic_store(flags + widx, val, __ATOMIC_RELAXED,
                           __HIP_MEMORY_SCOPE_AGENT);
}

__device__ __forceinline__ void waitgrp(const unsigned* __restrict__ mir,
                                        int mpage, int lane, unsigned tgt,
                                        int cg) {
    if (!tgt) return;
    const unsigned* mp = mir + mpage * 64 + cg * 4;   // groups 4cg..4cg+3
    for (;;) {
        unsigned v = __hip_atomic_load(mp + (lane & 3), __ATOMIC_RELAXED,
                                       __HIP_MEMORY_SCOPE_AGENT);
        if (__all(v >= tgt)) break;
        __builtin_amdgcn_s_sleep(1);
    }
    asm volatile("" ::: "memory");   // keep the chunk's loads below the wait
}

__device__ __forceinline__ void aggregator(unsigned* __restrict__ flags,
                                           unsigned* __restrict__ mir,
                                           int g, int lane) {
    for (unsigned e = 1; e <= 2u * TT - 1; ++e) {
        for (;;) {
            unsigned v = __hip_atomic_load(flags + g * 64 + lane,
                                           __ATOMIC_RELAXED,
                                           __HIP_MEMORY_SCOPE_AGENT);
            if (__all(v >= e)) break;
            __builtin_amdgcn_s_sleep(1);
        }
        if (lane < 8)
            __hip_atomic_store(mir + lane * 64 + g, e, __ATOMIC_RELAXED,
                               __HIP_MEMORY_SCOPE_AGENT);
        asm volatile("s_waitcnt vmcnt(0)" ::: "memory");  // keep mirrors monotone
    }
}

// ---------------------------------------------------------------------------
// One LSTM step. Phase 1: A1 chunks (recurrence-independent) load + MFMA —
// overlaps flag propagation. Phase 2: per-chunk waitgrp -> load -> MFMA,
// staggered (distance-1 load-ahead). Epilogue + sc1 h-store; publish at end
// (vmcnt(0) drain + lane-0 flag) — identical to the verified R5 ordering.
// Accumulation order identical (c ascending, accA/accB by f parity).
// ---------------------------------------------------------------------------
template <int NCH, int C1>
__device__ __forceinline__ void lstm_step(
    const short8* __restrict__ sW,
    const unsigned short* __restrict__ A1, int K1,
    const unsigned short* __restrict__ A2, int K2,
    const f32x4 bias, float& creg,
    unsigned short* __restrict__ hOut,        // [BB][HH] bf16 (fresh ring slot)
    unsigned* __restrict__ flags, unsigned* __restrict__ mir,
    int tgt, int widx, unsigned pub, int mpage,
    int lane, int q, int n, int j0, int u, int b)
{
    short8 av[3][8];
    auto aload = [&](short8* dst, int c) {
        const unsigned short* ap = (c < C1)
            ? A1 + (size_t)b * K1 + (size_t)c * 256
            : A2 + (size_t)b * K2 + (size_t)(c - C1) * 256;
        ap += q * 8;
        #pragma unroll
        for (int f = 0; f < 8; ++f) dst[f] = *(const short8*)(ap + f * 32);
    };

    f32x4 accA = {0.f, 0.f, 0.f, 0.f};
    f32x4 accB = {0.f, 0.f, 0.f, 0.f};

    // ---- phase 1: A1 chunks (no h_{t-1} dependency) ----
    aload(av[0], 0);
    if (C1 > 1) aload(av[1], 1);
    #pragma unroll
    for (int c = 0; c < C1; ++c) {
        if (c + 2 < C1) aload(av[(c + 2) % 3], c + 2);
        const short8* cur = av[c % 3];
        #pragma unroll
        for (int f = 0; f < 8; ++f) {
            short8 wv = sW[(c * 8 + f) * 64 + lane];
            if (f & 1) accB = __builtin_amdgcn_mfma_f32_16x16x32_bf16(wv, cur[f], accB, 0, 0, 0);
            else       accA = __builtin_amdgcn_mfma_f32_16x16x32_bf16(wv, cur[f], accA, 0, 0, 0);
        }
    }

    // ---- phase 2: A2 chunks, staggered per-group waits ----
    if (NCH > C1) {
        waitgrp(mir, mpage, lane, (unsigned)tgt, 0);
        aload(av[C1 % 3], C1);
        if (NCH > C1 + 1) {
            waitgrp(mir, mpage, lane, (unsigned)tgt, 1);
            aload(av[(C1 + 1) % 3], C1 + 1);
        }
        #pragma unroll
        for (int c = C1; c < NCH; ++c) {
            if (c + 2 < NCH) {
                waitgrp(mir, mpage, lane, (unsigned)tgt, c + 2 - C1);
                aload(av[(c + 2) % 3], c + 2);
            }
            const short8* cur = av[c % 3];
            #pragma unroll
            for (int f = 0; f < 8; ++f) {
                short8 wv = sW[(c * 8 + f) * 64 + lane];
                if (f & 1) accB = __builtin_amdgcn_mfma_f32_16x16x32_bf16(wv, cur[f], accB, 0, 0, 0);
                else       accA = __builtin_amdgcn_mfma_f32_16x16x32_bf16(wv, cur[f], accA, 0, 0, 0);
            }
        }
    }
    f32x4 acc = accA + accB;

    float pi = acc[0] + bias[0];
    float pf = acc[1] + bias[1];
    float pg = acc[2] + bias[2];
    float po = acc[3] + bias[3];
    float iv = 1.f / (1.f + __expf(-pi));
    float fv = 1.f / (1.f + __expf(-pf));
    float gv = tanhf(pg);
    float ov = 1.f / (1.f + __expf(-po));
    float cn = fv * creg + iv * gv;
    creg = cn;
    float hn = ov * tanhf(cn);

    // pack 4 gate-units (q=0..3) for batch row b into one u64, write-through
    unsigned hv = (unsigned)f2bf(hn);
    unsigned v0 = (unsigned)__shfl((int)hv, n);
    unsigned v1 = (unsigned)__shfl((int)hv, n + 16);
    unsigned v2 = (unsigned)__shfl((int)hv, n + 32);
    unsigned v3 = (unsigned)__shfl((int)hv, n + 48);
    if (q == 0) {
        unsigned long long pk = (unsigned long long)(v0 | (v1 << 16)) |
                                ((unsigned long long)(v2 | (v3 << 16)) << 32);
        __hip_atomic_store((unsigned long long*)(hOut + (size_t)b * HH + j0), pk,
                           __ATOMIC_RELAXED, __HIP_MEMORY_SCOPE_AGENT);
    }
    if (pub) publish(flags, widx, pub);
}

// ---------------------------------------------------------------------------
// Persistent kernel: 512 enc + 512 dec steps. 256 blocks x 5 waves: waves
// 0-3 compute (4 hidden units x 16-batch tiles), wave 4 is the aggregator
// on every 16th block (idle-return otherwise). Weights staged to LDS once
// (104KB). Cell state c lives in a register the whole time.
// ---------------------------------------------------------------------------
__global__ __launch_bounds__(320, 1) void k_lstm_persist(
    const unsigned short* __restrict__ xB,     // [TT][BB][FF]
    const unsigned short* __restrict__ WihE,   // [4H][FF] bf16
    const unsigned short* __restrict__ WhhE,   // [4H][HH] bf16
    const float* __restrict__ bE,
    const unsigned short* __restrict__ WihD,   // [4H][HH] bf16
    const unsigned short* __restrict__ WhhD,   // [4H][HH] bf16
    const float* __restrict__ bD,
    unsigned short* __restrict__ encB,         // [TT][BB][HH] bf16 ring
    unsigned short* __restrict__ decR,         // [TT][BB][HH] bf16 ring
    unsigned* __restrict__ flags)              // [1024] flags + 8x64 mirrors
{
    __shared__ short8 sWe[NCHE * 8 * 64];      // 40KB
    __shared__ short8 sWd[NCHD * 8 * 64];      // 64KB

    const int tid  = threadIdx.x;
    const int lane = tid & 63;
    const int w    = tid >> 6;
    unsigned* mir  = flags + 1024;

    if (w == 4) {                              // aggregator / idle wave
        __syncthreads();
        if ((blockIdx.x & 15) == 0)
            aggregator(flags, mir, blockIdx.x >> 4, lane);
        return;
    }

    const int q    = lane >> 4;
    const int n    = lane & 15;
    const int j0   = blockIdx.x * 4;
    const int rrow = (n & 3) * HH + j0 + (n >> 2);
    const size_t SB = (size_t)BB * HH;
    const int widx  = blockIdx.x * 4 + w;
    const int mpage = blockIdx.x & 7;

    // ---- stage BOTH weight sets into LDS, fragment order (once) ----
    #pragma unroll
    for (int i = 0; i < 2 * NCHE; ++i) {
        int g = i * 4 + w;                     // frag id 0..NCHE*8-1
        int c = g >> 3, f = g & 7;
        const unsigned short* Wp; int Ks; int cl;
        if (c < 1) { Wp = WihE; Ks = FF; cl = c; }
        else       { Wp = WhhE; Ks = HH; cl = c - 1; }
        sWe[g * 64 + lane] =
            *(const short8*)(Wp + (size_t)rrow * Ks + (size_t)cl * 256 + f * 32 + q * 8);
    }
    #pragma unroll
    for (int i = 0; i < 2 * NCHD; ++i) {
        int g = i * 4 + w;
        int c = g >> 3, f = g & 7;
        const unsigned short* Wp; int cl;
        if (c < 4) { Wp = WihD; cl = c; }
        else       { Wp = WhhD; cl = c - 4; }
        sWd[g * 64 + lane] =
            *(const short8*)(Wp + (size_t)rrow * HH + (size_t)cl * 256 + f * 32 + q * 8);
    }
    __syncthreads();

    const int u = j0 + q;
    const int b = w * 16 + n;
    const f32x4 biasE = {bE[u], bE[HH + u], bE[2 * HH + u], bE[3 * HH + u]};
    const f32x4 biasD = {bD[u], bD[HH + u], bD[2 * HH + u], bD[3 * HH + u]};

    float creg = 0.f;

    // ---- encoder: step t waits epoch t (groups per chunk), publishes t+1 ----
    lstm_step<1, 1>(sWe, xB, FF, xB, FF, biasE, creg,
                    encB, flags, mir, 0, widx, 1u, mpage,
                    lane, q, n, j0, u, b);
    for (int t = 1; t < TT; ++t) {
        lstm_step<NCHE, 1>(sWe, xB + (size_t)t * BB * FF, FF,
                           encB + (size_t)(t - 1) * SB, HH,
                           biasE, creg, encB + (size_t)t * SB,
                           flags, mir, t, widx, (unsigned)(t + 1), mpage,
                           lane, q, n, j0, u, b);
    }

    // ---- decoder: h0 = enc h_T (encB[TT-1]), c continues in creg ----
    for (int t = 0; t < TT; ++t) {
        const unsigned short* A2 = (t == 0) ? encB + (size_t)(TT - 1) * SB
                                            : decR + (size_t)(t - 1) * SB;
        unsigned pub = (t == TT - 1) ? 0u : (unsigned)(TT + t + 1);
        lstm_step<NCHD, 4>(sWd, encB + (size_t)t * SB, HH, A2, HH,
                           biasD, creg, decR + (size_t)t * SB,
                           flags, mir, TT + t, widx, pub, mpage,
                           lane, q, n, j0, u, b);
    }
    // decR stores reach the coherence point (sc1); dispatch boundary
    // handles visibility for out_proj.
}

// ---------------------------------------------------------------------------
// Output projection from the bf16 decoder ring decR [TT][BB][HH].
// ---------------------------------------------------------------------------
__global__ __launch_bounds__(256) void k_out_proj_r(
    const unsigned short* __restrict__ decR,  // [TT][BB][HH]
    const float* __restrict__ Wout,           // [FF][HH]
    const float* __restrict__ bout,           // [FF]
    float* __restrict__ out)                  // [BB][TT][FF]
{
    int t  = blockIdx.x;
    int fg = blockIdx.y;
    const int lane = threadIdx.x & 63;
    const int wv   = __builtin_amdgcn_readfirstlane(threadIdx.x >> 6);
    const int f0   = fg * 64 + wv * 16;
    const unsigned short* a = decR + ((size_t)t * BB + lane) * HH;

    float acc[16];
    #pragma unroll
    for (int i = 0; i < 16; ++i) acc[i] = bout[f0 + i];

    for (int k8 = 0; k8 < HH / 8; ++k8) {
        short8 hv8 = *(const short8*)(a + k8 * 8);
        #pragma unroll
        for (int uu = 0; uu < 8; ++uu) {
            float hv = bf2f((unsigned short)hv8[uu]);
            #pragma unroll
            for (int i = 0; i < 16; ++i)
                acc[i] = fmaf(Wout[(size_t)(f0 + i) * HH + k8 * 8 + uu], hv, acc[i]);
        }
    }

    float* op = out + ((size_t)lane * TT + t) * FF + f0;
    #pragma unroll
    for (int i = 0; i < 16; i += 4) {
        float4 v = make_float4(acc[i], acc[i + 1], acc[i + 2], acc[i + 3]);
        *(float4*)(op + i) = v;
    }
}

// ---------------------------------------------------------------------------
// FALLBACK path (small workspace): round-4 verified per-step kernels.
// ---------------------------------------------------------------------------
template <int NCH>
__global__ __launch_bounds__(256) void k_step_lds(
    const unsigned short* __restrict__ A1, const unsigned short* __restrict__ W1, int K1,
    const unsigned short* __restrict__ A2, const unsigned short* __restrict__ W2, int K2,
    int C1,
    const float* __restrict__ bias,
    float* __restrict__ Cbuf,
    unsigned short* __restrict__ hOut,
    float* __restrict__ chunkOut)
{
    __shared__ short8 sW[NCH * 8 * 64];

    const int tid  = threadIdx.x;
    const int lane = tid & 63;
    const int w    = tid >> 6;
    const int q    = lane >> 4;
    const int n    = lane & 15;
    const int j0   = blockIdx.x * 4;
    const int rrow = (n & 3) * HH + j0 + (n >> 2);

    short8 av[3][8];

    auto aload = [&](short8* dst, int c) {
        const unsigned short* ap = (c < C1)
            ? A1 + (size_t)(w * 16 + n) * K1 + (size_t)c * 256
            : A2 + (size_t)(w * 16 + n) * K2 + (size_t)(c - C1) * 256;
        ap += q * 8;
        #pragma unroll
        for (int f = 0; f < 8; ++f) dst[f] = *(const short8*)(ap + f * 32);
    };

    aload(av[0], 0);
    if (NCH > 1) aload(av[1], 1);

    #pragma unroll
    for (int i = 0; i < 2 * NCH; ++i) {
        int g = i * 4 + w;
        int c = g >> 3, f = g & 7;
        const unsigned short* Wp; int Ks; int cl;
        if (c < C1) { Wp = W1; Ks = K1; cl = c; }
        else        { Wp = W2; Ks = K2; cl = c - C1; }
        sW[g * 64 + lane] =
            *(const short8*)(Wp + (size_t)rrow * Ks + (size_t)cl * 256 + f * 32 + q * 8);
    }
    __syncthreads();

    f32x4 accA = {0.f, 0.f, 0.f, 0.f};
    f32x4 accB = {0.f, 0.f, 0.f, 0.f};
    #pragma unroll
    for (int c = 0; c < NCH; ++c) {
        if (c + 2 < NCH) aload(av[(c + 2) % 3], c + 2);
        const short8* cur = av[c % 3];
        #pragma unroll
        for (int f = 0; f < 8; ++f) {
            short8 wv = sW[(c * 8 + f) * 64 + lane];
            if (f & 1) accB = __builtin_amdgcn_mfma_f32_16x16x32_bf16(wv, cur[f], accB, 0, 0, 0);
            else       accA = __builtin_amdgcn_mfma_f32_16x16x32_bf16(wv, cur[f], accA, 0, 0, 0);
        }
    }
    f32x4 acc = accA + accB;

    const int u = j0 + q;
    const int b = w * 16 + n;
    float pi = acc[0] + bias[u];
    float pf = acc[1] + bias[HH + u];
    float pg = acc[2] + bias[2 * HH + u];
    float po = acc[3] + bias[3 * HH + u];
    float iv = 1.f / (1.f + __expf(-pi));
    float fv = 1.f / (1.f + __expf(-pf));
    float gv = tanhf(pg);
    float ov = 1.f / (1.f + __expf(-po));
    size_t cix = (size_t)u * BB + b;
    float c  = Cbuf[cix];
    float cn = fv * c + iv * gv;
    Cbuf[cix] = cn;
    float hn = ov * tanhf(cn);
    hOut[(size_t)b * HH + u] = f2bf(hn);
    if (chunkOut) chunkOut[cix] = hn;
}

__device__ __forceinline__ void seg_f32(const unsigned short* __restrict__ ap0,
                                        const float* __restrict__ wp0,
                                        int nch, f32x4& acc) {
    const unsigned short* ap = ap0;
    const float* wp = wp0;
    #pragma unroll 2
    for (int c = 0; c < nch; ++c) {
        float4 wa = *(const float4*)wp;
        float4 wb = *(const float4*)(wp + 4);
        short8 av = *(const short8*)ap;
        short8 wv;
        wv[0] = (short)f2bf(wa.x); wv[1] = (short)f2bf(wa.y);
        wv[2] = (short)f2bf(wa.z); wv[3] = (short)f2bf(wa.w);
        wv[4] = (short)f2bf(wb.x); wv[5] = (short)f2bf(wb.y);
        wv[6] = (short)f2bf(wb.z); wv[7] = (short)f2bf(wb.w);
        acc = __builtin_amdgcn_mfma_f32_16x16x32_bf16(wv, av, acc, 0, 0, 0);
        ap += 32; wp += 32;
    }
}

__global__ __launch_bounds__(256) void k_step_f32w(
    const unsigned short* __restrict__ A1, const float* __restrict__ W1, int K1,
    const unsigned short* __restrict__ A2, const float* __restrict__ W2, int K2,
    const float* __restrict__ bias,
    float* __restrict__ Cbuf, unsigned short* __restrict__ hOut,
    float* __restrict__ chunkOut)
{
    const int tid  = threadIdx.x;
    const int lane = tid & 63;
    const int w    = tid >> 6;
    const int q    = lane >> 4;
    const int n    = lane & 15;
    const int j0   = blockIdx.x * 4;
    const int rrow = (n & 3) * HH + j0 + (n >> 2);

    f32x4 acc = {0.f, 0.f, 0.f, 0.f};
    seg_f32(A1 + (size_t)(w * 16 + n) * K1 + q * 8,
            W1 + (size_t)rrow * K1 + q * 8, K1 >> 5, acc);
    if (K2)
        seg_f32(A2 + (size_t)(w * 16 + n) * HH + q * 8,
                W2 + (size_t)rrow * HH + q * 8, HH >> 5, acc);

    const int u = j0 + q;
    const int b = w * 16 + n;
    float pi = acc[0] + bias[u];
    float pf = acc[1] + bias[HH + u];
    float pg = acc[2] + bias[2 * HH + u];
    float po = acc[3] + bias[3 * HH + u];
    float iv = 1.f / (1.f + __expf(-pi));
    float fv = 1.f / (1.f + __expf(-pf));
    float gv = tanhf(pg);
    float ov = 1.f / (1.f + __expf(-po));
    size_t cix = (size_t)u * BB + b;
    float c  = Cbuf[cix];
    float cn = fv * c + iv * gv;
    Cbuf[cix] = cn;
    float hn = ov * tanhf(cn);
    hOut[(size_t)b * HH + u] = f2bf(hn);
    if (chunkOut) chunkOut[cix] = hn;
}

__global__ __launch_bounds__(256) void k_out_proj(
    const float* __restrict__ chunk,  // [C][HH][BB]
    const float* __restrict__ Wout,
    const float* __restrict__ bout,
    float* __restrict__ out,
    int t0)
{
    int tl = blockIdx.x;
    int t  = t0 + tl;
    int fg = blockIdx.y;
    const int lane = threadIdx.x & 63;
    const int wv   = __builtin_amdgcn_readfirstlane(threadIdx.x >> 6);
    const int f0   = fg * 64 + wv * 16;
    const float* a = chunk + (size_t)tl * HH * BB;

    float acc[16];
    #pragma unroll
    for (int i = 0; i < 16; ++i) acc[i] = bout[f0 + i];

    for (int k = 0; k < HH; k += 4) {
        #pragma unroll
        for (int u = 0; u < 4; ++u) {
            float hv = a[(size_t)(k + u) * BB + lane];
            #pragma unroll
            for (int i = 0; i < 16; ++i)
                acc[i] = fmaf(Wout[(size_t)(f0 + i) * HH + k + u], hv, acc[i]);
        }
    }

    float* op = out + ((size_t)lane * TT + t) * FF + f0;
    #pragma unroll
    for (int i = 0; i < 16; i += 4) {
        float4 v = make_float4(acc[i], acc[i + 1], acc[i + 2], acc[i + 3]);
        *(float4*)(op + i) = v;
    }
}

// ---------------------------------------------------------------------------
extern "C" void kernel_launch(void* const* d_in, const int* in_sizes, int n_in,
                              void* d_out, int out_size, void* d_ws, size_t ws_size,
                              hipStream_t stream) {
    const float* x     = (const float*)d_in[0];
    const float* Wih_e = (const float*)d_in[1];
    const float* Whh_e = (const float*)d_in[2];
    const float* b_e   = (const float*)d_in[3];
    const float* Wih_d = (const float*)d_in[4];
    const float* Whh_d = (const float*)d_in[5];
    const float* b_d   = (const float*)d_in[6];
    const float* Wout  = (const float*)d_in[7];
    const float* bout  = (const float*)d_in[8];
    float* out = (float*)d_out;

    const size_t SB = (size_t)BB * HH;            // 65536 elems per state

    unsigned short* xB = (unsigned short*)d_out;  // [TT][BB][FF] bf16

    // ================= persistent-kernel tier (~154MB ws) =================
    {
        char* p = (char*)d_ws;
        unsigned* flags = (unsigned*)p; p += 8192;  // 1024 flags + 8x64 mirror
        unsigned short* encB  = (unsigned short*)p; p += (size_t)TT * SB * 2;   // 64MB
        unsigned short* decR  = (unsigned short*)p; p += (size_t)TT * SB * 2;   // 64MB
        unsigned short* WihEb = (unsigned short*)p; p += (size_t)4 * HH * FF * 2;
        unsigned short* WhhEb = (unsigned short*)p; p += (size_t)4 * HH * HH * 2;
        unsigned short* WihDb = (unsigned short*)p; p += (size_t)4 * HH * HH * 2;
        unsigned short* WhhDb = (unsigned short*)p; p += (size_t)4 * HH * HH * 2;
        size_t need = (size_t)(p - (char*)d_ws);

        if (ws_size >= need) {
            hipMemsetAsync(flags, 0, 8192, stream);
            k_cast_x<<<TT, 256, 0, stream>>>(x, xB);
            k_wcast<<<1024, 256, 0, stream>>>(Wih_e, WihEb, 4 * HH * FF / 4);
            k_wcast<<<1024, 256, 0, stream>>>(Whh_e, WhhEb, 4 * HH * HH / 4);
            k_wcast<<<1024, 256, 0, stream>>>(Wih_d, WihDb, 4 * HH * HH / 4);
            k_wcast<<<1024, 256, 0, stream>>>(Whh_d, WhhDb, 4 * HH * HH / 4);

            void* args[] = {
                (void*)&xB, (void*)&WihEb, (void*)&WhhEb, (void*)&b_e,
                (void*)&WihDb, (void*)&WhhDb, (void*)&b_d,
                (void*)&encB, (void*)&decR, (void*)&flags};
            hipLaunchCooperativeKernel((const void*)k_lstm_persist,
                                       dim3(NBLK), dim3(320), args, 0, stream);

            k_out_proj_r<<<dim3(TT, 4), 256, 0, stream>>>(decR, Wout, bout, out);
            return;
        }
    }

    // ================= fallback: round-4 verified path =================
    char* p = (char*)d_ws;
    unsigned short* encB  = (unsigned short*)p; p += (size_t)TT * SB * 2;
    unsigned short* dech0 = (unsigned short*)p; p += SB * 2;
    unsigned short* dech1 = (unsigned short*)p; p += SB * 2;
    float* cbuf = (float*)p; p += SB * 4;
    size_t used  = (size_t)(p - (char*)d_ws);
    size_t avail = ws_size > used ? ws_size - used : 0;

    const size_t WE_B = ((size_t)4 * HH * FF + (size_t)4 * HH * HH) * 2;
    const size_t WD_B = ((size_t)4 * HH * HH) * 2 * 2;
    const size_t CH8  = (size_t)8 * SB * 4;

    bool wbAll = (avail >= WE_B + WD_B + CH8);
    bool wbEnc = wbAll || (avail >= WE_B + CH8);

    unsigned short *WihEb = 0, *WhhEb = 0, *WihDb = 0, *WhhDb = 0;
    if (wbEnc) {
        WihEb = (unsigned short*)p; p += (size_t)4 * HH * FF * 2;
        WhhEb = (unsigned short*)p; p += (size_t)4 * HH * HH * 2;
        avail -= WE_B;
    }
    if (wbAll) {
        WihDb = (unsigned short*)p; p += (size_t)4 * HH * HH * 2;
        WhhDb = (unsigned short*)p; p += (size_t)4 * HH * HH * 2;
        avail -= WD_B;
    }
    int C = 8;
    if      (avail >= (size_t)64 * SB * 4) C = 64;
    else if (avail >= (size_t)32 * SB * 4) C = 32;
    else if (avail >= (size_t)16 * SB * 4) C = 16;
    float* chunk = (float*)p;

    hipMemsetAsync(cbuf, 0, SB * 4, stream);
    k_cast_x<<<TT, 256, 0, stream>>>(x, xB);
    if (wbEnc) {
        k_wcast<<<1024, 256, 0, stream>>>(Wih_e, WihEb, 4 * HH * FF / 4);
        k_wcast<<<1024, 256, 0, stream>>>(Whh_e, WhhEb, 4 * HH * HH / 4);
    }
    if (wbAll) {
        k_wcast<<<1024, 256, 0, stream>>>(Wih_d, WihDb, 4 * HH * HH / 4);
        k_wcast<<<1024, 256, 0, stream>>>(Whh_d, WhhDb, 4 * HH * HH / 4);
    }

    for (int t = 0; t < TT; ++t) {
        const unsigned short* A1 = xB + (size_t)t * BB * FF;
        const unsigned short* A2 = t ? encB + (size_t)(t - 1) * SB : (unsigned short*)0;
        unsigned short* hOut = encB + (size_t)t * SB;
        if (wbEnc) {
            if (t == 0)
                k_step_lds<1><<<256, 256, 0, stream>>>(A1, WihEb, FF, A2, WhhEb, HH,
                                                       1, b_e, cbuf, hOut, (float*)0);
            else
                k_step_lds<5><<<256, 256, 0, stream>>>(A1, WihEb, FF, A2, WhhEb, HH,
                                                       1, b_e, cbuf, hOut, (float*)0);
        } else {
            k_step_f32w<<<256, 256, 0, stream>>>(A1, Wih_e, FF, A2, Whh_e,
                                                 t ? HH : 0, b_e, cbuf, hOut, (float*)0);
        }
    }

    for (int t = 0; t < TT; ++t) {
        const unsigned short* A1 = encB + (size_t)t * SB;
        const unsigned short* A2 = (t == 0) ? encB + (size_t)(TT - 1) * SB
                                            : ((t & 1) ? dech1 : dech0);
        unsigned short* hOut = ((t + 1) & 1) ? dech1 : dech0;
        int l = t & (C - 1);
        float* ch = chunk + (size_t)l * SB;
        if (wbAll)
            k_step_lds<8><<<256, 256, 0, stream>>>(A1, WihDb, HH, A2, WhhDb, HH,
                                                   4, b_d, cbuf, hOut, ch);
        else
            k_step_f32w<<<256, 256, 0, stream>>>(A1, Wih_d, FF, A2, Whh_d, HH,
                                                 b_d, cbuf, hOut, ch);
        if (l == C - 1)
            k_out_proj<<<dim3(C, 4), 256, 0, stream>>>(chunk, Wout, bout, out,
                                                       t - (C - 1));
    }
}